// Round 5
// baseline (648.792 us; speedup 1.0000x reference)
//
#include <hip/hip_runtime.h>
#include <math.h>

typedef unsigned short u16;
typedef __attribute__((ext_vector_type(4))) float f32x4;
typedef __attribute__((ext_vector_type(8))) __bf16 bf16x8;
typedef __attribute__((ext_vector_type(4))) unsigned short u16x4;
typedef __attribute__((ext_vector_type(8))) unsigned short u16x8;

// async global->LDS, 16B per lane; LDS dest must be wave-uniform base + lane*16
#define GLL16(gp, lp) __builtin_amdgcn_global_load_lds( \
    (__attribute__((address_space(1))) void*)(void*)(gp), \
    (__attribute__((address_space(3))) void*)(void*)(lp), 16, 0, 0)

__device__ __forceinline__ u16 f2bf(float x) {            // RNE
    unsigned u = __float_as_uint(x);
    return (u16)((u + 0x7FFFu + ((u >> 16) & 1u)) >> 16);
}
__device__ __forceinline__ float bf2f(u16 h) { return __uint_as_float(((unsigned)h) << 16); }

__device__ __forceinline__ f32x4 mfma16(bf16x8 a, bf16x8 b, f32x4 c) {
    return __builtin_amdgcn_mfma_f32_16x16x32_bf16(a, b, c, 0, 0, 0);
}

// ---------------- fp32 -> bf16 conversion ----------------
__global__ void cvt_f32_bf16(const float* __restrict__ s, u16* __restrict__ d, int n4) {
    int i = blockIdx.x * 256 + threadIdx.x;
    if (i < n4) {
        float4 v = ((const float4*)s)[i];
        u16x4 o = { f2bf(v.x), f2bf(v.y), f2bf(v.z), f2bf(v.w) };
        ((u16x4*)d)[i] = o;
    }
}

// ---------------- rope table: cos/sin of 2*theta (double rotary = rotate by 2theta) ----
__global__ void rope_table_k(float2* __restrict__ tab) {
    int id = blockIdx.x * 256 + threadIdx.x;   // 2048*64
    int t = id >> 6, j = id & 63;
    float freq = exp2f(-((float)(2 * j) / 128.f) * 13.287712379549449f);
    float ang = 2.f * (float)t * freq;
    float sv, cv;
    sincosf(ang, &sv, &cv);
    float2 r; r.x = cv; r.y = sv;
    tab[id] = r;
}

// ---------------- NT GEMM: C[m][n] = sum_k A[m][k] * B[n][k] ----------------
// 256x256 tile, BK=64, 512 thr / 8 waves (2M x 4N), wave tile 128x64, acc[8][4].
// LDS 128KB: slot s at s*32768 u16 (A 256x64 @+0, B 256x64 @+16384).
// 8-phase / 2-K-tile schedule, NO sched_barrier (R4's spill cause). Per phase:
//   { ds_reads ; stage 1 half ; [vmcnt@P3,P7] ; s_barrier ; lgkmcnt(0) ;
//     setprio(1) 16xMFMA setprio(0) ; s_barrier }
// Quadrant snake per slot: P0 Q00(rd A-off0 12, B-off0), P1 Q01(rd B-off2),
// P2 Q11(rd A-off4), P3 Q10(no reads). P4-P7 same on slot1.
// Region lifetimes (BOTH halves): A read at P0+P2, B read at P0+P1 (per slot).
// Staging spread (each after its region's drain = tail barrier of last read phase):
//   P0: slot1.A-h0[t1]   P1: slot1.A-h1[t1]    (gated by vmcnt@P3 this iter)
//   P2: slot0.B-h0[t0+2] P3: slot0.B-h1[t0+2]  (B[t0] drained at tail_P1)
//   P4: slot0.A-h0[t0+2] P5: slot0.A-h1[t0+2]  (A[t0] drained at tail_P2)
//   P6: slot1.B-h0[t1+2] P7: slot1.B-h1[t1+2]  (B'[t1] drained at tail_P5)
// Gates (outstanding-count verified): vmcnt(4) before P3-top (completes slot1 t1
// = P6,P7 prev + P0,P1 cur; leaves P2,P3) and before P7-top (completes slot0
// t0+2 = P2..P5; leaves P6,P7). Last iter: vmcnt(0)@P3, no gate @P7.
// Source-side XOR swizzle kc^=row&7 (linear LDS dest for global_load_lds).
// MODE 0: fused QKV; rope+scale epilogue (2 heads per n-tile); V transposed.
// MODE 1: fp32 Out (M x 2048)
template <int MODE>
__global__ __launch_bounds__(512, 2) void gemm_nt(const u16* __restrict__ A, const u16* __restrict__ Bw,
                                                  u16* __restrict__ Qo, u16* __restrict__ Ko,
                                                  u16* __restrict__ Vt, float* __restrict__ Out,
                                                  const float2* __restrict__ tab, float qscale, int K) {
    extern __shared__ u16 smem[];   // 65536 u16 = 128KB
    const int tid = threadIdx.x;
    const int lane = tid & 63;
    const int qd = lane >> 4, ln = lane & 15;
    const int wid = tid >> 6;             // 0..7
    const int wr = wid >> 2, wc = wid & 3;

    constexpr int NBY = (MODE == 0) ? 24 : 8;
    const int id = (int)blockIdx.x;
    const int xcd = id & 7, slot = id >> 3;
    const int m0 = ((slot / NBY) * 8 + xcd) * 256;
    const int n0 = (slot % NBY) * 256;

    // staging geometry: half-tile = 128 rows x 64 k = 1024 chunks, 2/thread
    int sr[2], skc[2];
#pragma unroll
    for (int l = 0; l < 2; ++l) {
        const int i = l * 512 + tid;
        sr[l] = i >> 3;
        skc[l] = (i & 7) ^ (sr[l] & 7);
    }

    auto stage = [&](int tt, int hx) {    // hx: 0=A-h0 1=A-h1 2=B-h0 3=B-h1
        const u16* gp = (hx < 2) ? A : Bw;
        const int x0 = (hx < 2) ? m0 : n0;
        const int h = hx & 1;
        u16* lb = &smem[(tt & 1) * 32768 + (hx >> 1) * 16384 + h * 8192];
#pragma unroll
        for (int l = 0; l < 2; ++l)
            GLL16(gp + (size_t)(x0 + 128 * h + sr[l]) * K + tt * 64 + skc[l] * 8,
                  &lb[(l * 512 + tid) * 8]);
    };

    f32x4 acc[8][4];
#pragma unroll
    for (int mi = 0; mi < 8; ++mi)
#pragma unroll
        for (int ni = 0; ni < 4; ++ni) acc[mi][ni] = f32x4{0.f, 0.f, 0.f, 0.f};

    const int arow = (wr * 128 + ln) * 64;
    const int brow = (wc * 64 + ln) * 64;
    const int cxk[2] = { (qd ^ (ln & 7)) * 8, ((qd + 4) ^ (ln & 7)) * 8 };

    auto rdA = [&](const u16* As, bf16x8 (&af)[4][2], int off) {
#pragma unroll
        for (int mi = 0; mi < 4; ++mi)
#pragma unroll
            for (int ks = 0; ks < 2; ++ks)
                af[mi][ks] = *(const bf16x8*)&As[arow + (mi + off) * 1024 + cxk[ks]];
    };
    auto rdB = [&](const u16* Bs, bf16x8 (&bb)[2][2], int off) {
#pragma unroll
        for (int ni = 0; ni < 2; ++ni)
#pragma unroll
            for (int ks = 0; ks < 2; ++ks)
                bb[ni][ks] = *(const bf16x8*)&Bs[brow + (ni + off) * 1024 + cxk[ks]];
    };
    auto clus = [&](bf16x8 (&af)[4][2], bf16x8 (&bb)[2][2], int mo, int no) {
        __builtin_amdgcn_s_setprio(1);
#pragma unroll
        for (int mi = 0; mi < 4; ++mi)
#pragma unroll
            for (int ni = 0; ni < 2; ++ni)
#pragma unroll
                for (int ks = 0; ks < 2; ++ks)
                    acc[mi + mo][ni + no] = mfma16(af[mi][ks], bb[ni][ks], acc[mi + mo][ni + no]);
        __builtin_amdgcn_s_setprio(0);
    };
#define PBAR asm volatile("s_barrier" ::: "memory")
#define LGK0 asm volatile("s_waitcnt lgkmcnt(0)" ::: "memory")

    const int niter = K >> 6;   // 32 K-tiles
    const int L = niter >> 1;   // 16 iterations
    // prologue: T0 {Bh0,Bh1,Ah0,Ah1} + T1 {Bh0,Bh1}; gate T0 (leave T1's 4 loads)
    stage(0, 2); stage(0, 3); stage(0, 0); stage(0, 1);
    stage(1, 2); stage(1, 3);
    asm volatile("s_waitcnt vmcnt(4)" ::: "memory");
    asm volatile("s_barrier" ::: "memory");

    for (int i = 0; i < L; ++i) {
        const int t0 = 2 * i, t1 = 2 * i + 1;
        const u16* As0 = &smem[0];
        const u16* Bs0 = &smem[16384];
        const u16* As1 = &smem[32768];
        const u16* Bs1 = &smem[49152];
        const bool lastit = (i == L - 1);
        bf16x8 a0[4][2], a1[4][2], b0[2][2], b1[2][2];

        // ---- P0: Q00 slot0 ----
        rdA(As0, a0, 0); rdB(Bs0, b0, 0);
        stage(t1, 0);
        PBAR; LGK0; clus(a0, b0, 0, 0); PBAR;
        // ---- P1: Q01 slot0 ----
        rdB(Bs0, b1, 2);
        stage(t1, 1);
        PBAR; LGK0; clus(a0, b1, 0, 2); PBAR;
        // ---- P2: Q11 slot0 ----
        rdA(As0, a1, 4);
        if (!lastit) stage(t0 + 2, 2);
        PBAR; LGK0; clus(a1, b1, 4, 2); PBAR;
        // ---- P3: Q10 slot0 (no reads) ---- gate slot1 tile t1
        if (!lastit) {
            stage(t0 + 2, 3);
            asm volatile("s_waitcnt vmcnt(4)" ::: "memory");
        } else {
            asm volatile("s_waitcnt vmcnt(0)" ::: "memory");
        }
        PBAR; clus(a1, b0, 4, 0); PBAR;
        // ---- P4: Q00 slot1 ----
        rdA(As1, a0, 0); rdB(Bs1, b0, 0);
        if (!lastit) stage(t0 + 2, 0);
        PBAR; LGK0; clus(a0, b0, 0, 0); PBAR;
        // ---- P5: Q01 slot1 ----
        rdB(Bs1, b1, 2);
        if (!lastit) stage(t0 + 2, 1);
        PBAR; LGK0; clus(a0, b1, 0, 2); PBAR;
        // ---- P6: Q11 slot1 ----
        rdA(As1, a1, 4);
        if (!lastit) stage(t1 + 2, 2);
        PBAR; LGK0; clus(a1, b1, 4, 2); PBAR;
        // ---- P7: Q10 slot1 (no reads) ---- gate slot0 tile t0+2
        if (!lastit) {
            stage(t1 + 2, 3);
            asm volatile("s_waitcnt vmcnt(4)" ::: "memory");
        }
        PBAR; clus(a1, b0, 4, 0); PBAR;
    }
#undef PBAR
#undef LGK0
    __syncthreads();   // K-loop LDS dead; epilogue reuses all 128KB

    if constexpr (MODE == 0) {
        const int sec = n0 >> 11;   // 0=Q 1=K 2=V, uniform per block
        if (sec <= 1) {
            // stage C tile [m 256][d 256] bf16, chunk-swizzled: chunk' = (d>>3) ^ (m&15)
#pragma unroll
            for (int mi = 0; mi < 8; ++mi)
#pragma unroll
                for (int ni = 0; ni < 4; ++ni) {
                    const int col = wc * 64 + ni * 16 + ln;
                    const int cc = col >> 3, co = col & 7;
#pragma unroll
                    for (int r = 0; r < 4; ++r) {
                        const int row = wr * 128 + mi * 16 + qd * 4 + r;
                        smem[row * 256 + ((cc ^ (row & 15)) * 8) + co] = f2bf(acc[mi][ni][r]);
                    }
                }
            __syncthreads();
            const float qs = (sec == 0) ? qscale : 1.0f;
            u16* dstb = (sec == 0 ? Qo : Ko);
#pragma unroll
            for (int it = 0; it < 8; ++it) {
                const int c = it * 512 + tid;    // 4096 items: m (256) x head-in-tile (2) x lo-octet (8)
                const int m = c >> 4, hh = (c >> 3) & 1, d8 = c & 7;
                const u16x8 lo = *(const u16x8*)&smem[m * 256 + (((hh * 16 + d8) ^ (m & 15)) * 8)];
                const u16x8 hi = *(const u16x8*)&smem[m * 256 + (((hh * 16 + 8 + d8) ^ (m & 15)) * 8)];
                const int t = (m0 + m) & 2047;
                const float2* tb = tab + t * 64 + d8 * 8;
                u16x8 o1, o2;
#pragma unroll
                for (int i = 0; i < 8; ++i) {
                    const float x1 = bf2f(lo[i]), x2 = bf2f(hi[i]);
                    const float2 cs = tb[i];
                    o1[i] = f2bf((x1 * cs.x + x2 * cs.y) * qs);
                    o2[i] = f2bf((x2 * cs.x - x1 * cs.y) * qs);
                }
                u16* dst = dstb + (size_t)(m0 + m) * 2048 + (n0 & 2047) + hh * 128 + d8 * 8;
                *(u16x8*)dst = o1;
                *(u16x8*)(dst + 64) = o2;
            }
        } else {
            // V transpose: stage [nl 256][m 256] chunk-swizzled, stream rows of Vt
            const int bb = m0 >> 11;
#pragma unroll
            for (int mi = 0; mi < 8; ++mi) {
                const int mbase = wr * 128 + mi * 16 + qd * 4;
                const int mch = mbase >> 3, moff = mbase & 7;
#pragma unroll
                for (int ni = 0; ni < 4; ++ni) {
                    const int nl = wc * 64 + ni * 16 + ln;
                    u16x4 pk = { f2bf(acc[mi][ni][0]), f2bf(acc[mi][ni][1]),
                                 f2bf(acc[mi][ni][2]), f2bf(acc[mi][ni][3]) };
                    *(u16x4*)&smem[nl * 256 + ((mch ^ (nl & 15)) * 8) + moff] = pk;
                }
            }
            __syncthreads();
#pragma unroll
            for (int i = 0; i < 16; ++i) {
                const int c = i * 512 + tid;     // 8192 chunks
                const int nl = c >> 5, ch = c & 31;
                const u16x8 v = *(const u16x8*)&smem[nl * 256 + ch * 8];
                const int mch = ch ^ (nl & 15);
                const int hd = (n0 - 4096) + nl;
                *(u16x8*)&Vt[((size_t)(bb * 2048 + hd)) * 2048 + (m0 & 2047) + mch * 8] = v;
            }
        }
    } else {
        const int mg0 = m0 + wr * 128 + qd * 4;
        const int ng0 = n0 + wc * 64 + ln;
#pragma unroll
        for (int mi = 0; mi < 8; ++mi)
#pragma unroll
            for (int ni = 0; ni < 4; ++ni) {
                const int ng = ng0 + ni * 16;
#pragma unroll
                for (int r = 0; r < 4; ++r)
                    Out[(size_t)(mg0 + mi * 16 + r) * 2048 + ng] = acc[mi][ni][r];
            }
    }
}

// ---------------- causal flash attention ----------------
// 512 threads (8 waves x 16 q-rows), paired q-tiles {15-px, px} per block -> every
// block does exactly 34 k-iterations. 80KB LDS -> 2 blocks/CU -> 16 waves/CU.
// K-loop: raw s_barrier + counted vmcnt(4).
__global__ __launch_bounds__(512, 4) void attn_kernel(const u16* __restrict__ Qb, const u16* __restrict__ Kb,
                                                      const u16* __restrict__ Vt, u16* __restrict__ Yb) {
    extern __shared__ u16 smem[];
    u16* QP = smem;                 // 8192 u16: Q stage (64x128) / P buf (128x64)
    u16* KsB = smem + 8192;         // 2 x 8192 u16
    u16* VsB = smem + 8192 + 16384; // 2 x 8192 u16

    const int tid = threadIdx.x;
    const int lane = tid & 63;
    const int qd = lane >> 4, ln = lane & 15;
    const int wid = tid >> 6;            // 0..7
    const int id = (int)blockIdx.x;
    const int px = id >> 6;              // 0..7
    const int bh = id & 63;
    const int b = bh >> 4, h = bh & 15;

    const u16* Qbh = Qb + ((size_t)b * 2048 * 16 + h) * 128;
    const u16* Kbh = Kb + ((size_t)b * 2048 * 16 + h) * 128;
    const u16* Vbh = Vt + ((size_t)(b * 16 + h) * 128) * 2048;

    int lC[2], kOff[2], vOff[2];
#pragma unroll
    for (int p = 0; p < 2; ++p) {
        const int c = p * 512 + tid;     // 0..1023
        lC[p] = c * 8;
        { const int r = c >> 4, cc = (c & 15) ^ (r & 7); kOff[p] = r * 2048 + cc * 8; }
        { const int rv = c >> 3, cc = (c & 7) ^ (rv & 7); vOff[p] = rv * 2048 + cc * 8; }
    }

    bf16x8 onesf;
#pragma unroll
    for (int i = 0; i < 8; ++i) onesf[i] = (__bf16)1.0f;

    for (int half = 0; half < 2; ++half) {
        const int qt = half ? px : (15 - px);   // heavy tile first
        const int q0 = qt * 128;
        const int wq = q0 + wid * 16;
        const int nkt = 2 * qt + 2;

        __syncthreads();   // all waves done with QP (P buffer) before restaging Q
#pragma unroll
        for (int p = 0; p < 2; ++p)
            GLL16(Qbh + (size_t)q0 * 2048 + kOff[p], &QP[lC[p]]);
        __syncthreads();
        bf16x8 qf[4];
        if (wid < 4) {
            const int lr = wid * 16 + ln;
#pragma unroll
            for (int ks = 0; ks < 4; ++ks)
                qf[ks] = *(const bf16x8*)&QP[lr * 128 + (((ks * 4 + qd) ^ (lr & 7)) * 8)];
        }
        __syncthreads();
#pragma unroll
        for (int p = 0; p < 2; ++p)
            GLL16(Qbh + (size_t)(q0 + 64) * 2048 + kOff[p], &QP[lC[p]]);
        __syncthreads();
        if (wid >= 4) {
            const int lr = (wid - 4) * 16 + ln;
#pragma unroll
            for (int ks = 0; ks < 4; ++ks)
                qf[ks] = *(const bf16x8*)&QP[lr * 128 + (((ks * 4 + qd) ^ (lr & 7)) * 8)];
        }
        __syncthreads();   // readers drained before k-loop P writes reuse QP

#pragma unroll
        for (int p = 0; p < 2; ++p) GLL16(Kbh + kOff[p], &KsB[lC[p]]);
#pragma unroll
        for (int p = 0; p < 2; ++p) GLL16(Vbh + vOff[p], &VsB[lC[p]]);

        f32x4 o[8];
#pragma unroll
        for (int di = 0; di < 8; ++di) o[di] = f32x4{0.f, 0.f, 0.f, 0.f};
        f32x4 lacc = f32x4{0.f, 0.f, 0.f, 0.f};
        float Mr[4];
#pragma unroll
        for (int r = 0; r < 4; ++r) Mr[r] = -1e30f;

        for (int kt = 0; kt < nkt; ++kt) {
            const int k0 = kt * 64;
            asm volatile("s_barrier" ::: "memory");
            if (kt + 1 < nkt) {
                u16* kd = KsB + ((kt + 1) & 1) * 8192;
                u16* vd = VsB + ((kt + 1) & 1) * 8192;
#pragma unroll
                for (int p = 0; p < 2; ++p) GLL16(Kbh + (size_t)(k0 + 64) * 2048 + kOff[p], &kd[lC[p]]);
#pragma unroll
                for (int p = 0; p < 2; ++p) GLL16(Vbh + (size_t)(k0 + 64) + vOff[p], &vd[lC[p]]);
                asm volatile("s_waitcnt vmcnt(4)" ::: "memory");
            } else {
                asm volatile("s_waitcnt vmcnt(0)" ::: "memory");
            }
            asm volatile("s_barrier" ::: "memory");

            if (k0 <= wq + 15) {
                const u16* Kc = KsB + (kt & 1) * 8192;
                const u16* Vc = VsB + (kt & 1) * 8192;
                f32x4 s[4];
#pragma unroll
                for (int ni = 0; ni < 4; ++ni) s[ni] = f32x4{0.f, 0.f, 0.f, 0.f};
#pragma unroll
                for (int ks = 0; ks < 4; ++ks) {
                    bf16x8 kf[4];
#pragma unroll
                    for (int ni = 0; ni < 4; ++ni) {
                        const int row = ni * 16 + ln;
                        kf[ni] = *(const bf16x8*)&Kc[row * 128 + (((ks * 4 + qd) ^ (ln & 7)) * 8)];
                    }
#pragma unroll
                    for (int ni = 0; ni < 4; ++ni)
                        s[ni] = mfma16(qf[ks], kf[ni], s[ni]);
                }
                if (k0 + 63 > wq) {
#pragma unroll
                    for (int ni = 0; ni < 4; ++ni)
#pragma unroll
                        for (int r = 0; r < 4; ++r) {
                            const int qi = wq + qd * 4 + r;
                            const int ki = k0 + ni * 16 + ln;
                            if (ki > qi) s[ni][r] = -1e30f;
                        }
                }
                float rx[4];
#pragma unroll
                for (int r = 0; r < 4; ++r)
                    rx[r] = fmaxf(fmaxf(s[0][r], s[1][r]), fmaxf(s[2][r], s[3][r]));
#pragma unroll
                for (int st = 1; st < 16; st <<= 1)
#pragma unroll
                    for (int r = 0; r < 4; ++r)
                        rx[r] = fmaxf(rx[r], __shfl_xor(rx[r], st));
                float al[4];
                bool need = false;
#pragma unroll
                for (int r = 0; r < 4; ++r) {
                    const float nm = fmaxf(Mr[r], rx[r]);
                    al[r] = exp2f(Mr[r] - nm);
                    Mr[r] = nm;
                    need |= (al[r] != 1.0f);
                }
                if (__any(need)) {
#pragma unroll
                    for (int r = 0; r < 4; ++r) lacc[r] *= al[r];
#pragma unroll
                    for (int di = 0; di < 8; ++di)
#pragma unroll
                        for (int r = 0; r < 4; ++r) o[di][r] *= al[r];
                }
#pragma unroll
                for (int ni = 0; ni < 4; ++ni) {
                    const int cc0 = ni * 2 + (ln >> 3);
#pragma unroll
                    for (int r = 0; r < 4; ++r) {
                        const float p = exp2f(s[ni][r] - Mr[r]);
                        const int prow = wid * 16 + qd * 4 + r;
                        QP[prow * 64 + ((cc0 ^ ((prow >> 1) & 7)) * 8) + (ln & 7)] = f2bf(p);
                    }
                }
#pragma unroll
                for (int ks2 = 0; ks2 < 2; ++ks2) {
                    const int prow = wid * 16 + ln;
                    bf16x8 pf = *(const bf16x8*)&QP[prow * 64 + (((ks2 * 4 + qd) ^ ((prow >> 1) & 7)) * 8)];
                    lacc = mfma16(pf, onesf, lacc);
#pragma unroll
                    for (int di = 0; di < 8; ++di) {
                        const int row = di * 16 + ln;
                        bf16x8 vf = *(const bf16x8*)&Vc[row * 64 + (((ks2 * 4 + qd) ^ (ln & 7)) * 8)];
                        o[di] = mfma16(pf, vf, o[di]);
                    }
                }
            }
        }

        float inv[4];
#pragma unroll
        for (int r = 0; r < 4; ++r) inv[r] = 1.f / lacc[r];
#pragma unroll
        for (int di = 0; di < 8; ++di)
#pragma unroll
            for (int r = 0; r < 4; ++r) {
                const int t = q0 + wid * 16 + qd * 4 + r;
                const int d = di * 16 + ln;
                Yb[((size_t)((b * 2048 + t) * 16 + h)) * 128 + d] = f2bf(o[di][r] * inv[r]);
            }
    }
}

// ---------------- launch ----------------
extern "C" void kernel_launch(void* const* d_in, const int* in_sizes, int n_in,
                              void* d_out, int out_size, void* d_ws, size_t ws_size,
                              hipStream_t stream) {
    const float* x  = (const float*)d_in[0];
    const float* wq = (const float*)d_in[1];
    const float* wk = (const float*)d_in[2];
    const float* wv = (const float*)d_in[3];
    const float* wo = (const float*)d_in[4];
    float* out = (float*)d_out;
    char* ws = (char*)d_ws;

    u16* xb     = (u16*)(ws);                          // 8192x2048 bf16; reused as Y after attn
    u16* wqkv   = (u16*)(ws + (size_t)33554432);       // 6144x2048 bf16
    u16* wob    = (u16*)(ws + (size_t)58720256);       // 2048x2048 bf16
    u16* Qb     = (u16*)(ws + (size_t)67108864);       // (B,T,H,D) bf16, pre-scaled by 1/sqrt(D)*log2e
    u16* Kb     = (u16*)(ws + (size_t)100663296);      // (B,T,H,D) bf16
    u16* Vt     = (u16*)(ws + (size_t)134217728);      // (B,H,D,T) bf16
    float2* tab = (float2*)(ws + (size_t)167772160);   // 2048x64 cos/sin(2theta)
    u16* Yb = xb;

    const float scl = 0.08838834764831845f * 1.4426950408889634f;

    cvt_f32_bf16<<<16384, 256, 0, stream>>>(x, xb, 4194304);
    cvt_f32_bf16<<<4096, 256, 0, stream>>>(wq, wqkv, 1048576);
    cvt_f32_bf16<<<4096, 256, 0, stream>>>(wk, wqkv + 4194304, 1048576);
    cvt_f32_bf16<<<4096, 256, 0, stream>>>(wv, wqkv + 8388608, 1048576);
    cvt_f32_bf16<<<4096, 256, 0, stream>>>(wo, wob, 1048576);
    rope_table_k<<<512, 256, 0, stream>>>(tab);

    hipFuncSetAttribute((const void*)gemm_nt<0>, hipFuncAttributeMaxDynamicSharedMemorySize, 131072);
    hipFuncSetAttribute((const void*)gemm_nt<1>, hipFuncAttributeMaxDynamicSharedMemorySize, 131072);

    gemm_nt<0><<<dim3(768), 512, 131072, stream>>>(xb, wqkv, Qb, Kb, Vt, nullptr, tab, scl, 2048);

    hipFuncSetAttribute((const void*)attn_kernel, hipFuncAttributeMaxDynamicSharedMemorySize, 81920);
    attn_kernel<<<dim3(512), 512, 81920, stream>>>(Qb, Kb, Vt, Yb);

    gemm_nt<1><<<dim3(256), 512, 131072, stream>>>(Yb, wob, nullptr, nullptr, nullptr, out, tab, 1.0f, 2048);
}

// Round 6
// 576.091 us; speedup vs baseline: 1.1262x; 1.1262x over previous
//
#include <hip/hip_runtime.h>
#include <math.h>

typedef unsigned short u16;
typedef __attribute__((ext_vector_type(4))) float f32x4;
typedef __attribute__((ext_vector_type(8))) __bf16 bf16x8;
typedef __attribute__((ext_vector_type(4))) unsigned short u16x4;
typedef __attribute__((ext_vector_type(8))) unsigned short u16x8;

// async global->LDS, 16B per lane; LDS dest must be wave-uniform base + lane*16
#define GLL16(gp, lp) __builtin_amdgcn_global_load_lds( \
    (__attribute__((address_space(1))) void*)(void*)(gp), \
    (__attribute__((address_space(3))) void*)(void*)(lp), 16, 0, 0)

__device__ __forceinline__ u16 f2bf(float x) {            // RNE
    unsigned u = __float_as_uint(x);
    return (u16)((u + 0x7FFFu + ((u >> 16) & 1u)) >> 16);
}
__device__ __forceinline__ float bf2f(u16 h) { return __uint_as_float(((unsigned)h) << 16); }

__device__ __forceinline__ f32x4 mfma16(bf16x8 a, bf16x8 b, f32x4 c) {
    return __builtin_amdgcn_mfma_f32_16x16x32_bf16(a, b, c, 0, 0, 0);
}

// ---------------- fp32 -> bf16 conversion ----------------
__global__ void cvt_f32_bf16(const float* __restrict__ s, u16* __restrict__ d, int n4) {
    int i = blockIdx.x * 256 + threadIdx.x;
    if (i < n4) {
        float4 v = ((const float4*)s)[i];
        u16x4 o = { f2bf(v.x), f2bf(v.y), f2bf(v.z), f2bf(v.w) };
        ((u16x4*)d)[i] = o;
    }
}

// ---------------- rope table: cos/sin of 2*theta (double rotary = rotate by 2theta) ----
__global__ void rope_table_k(float2* __restrict__ tab) {
    int id = blockIdx.x * 256 + threadIdx.x;   // 2048*64
    int t = id >> 6, j = id & 63;
    float freq = exp2f(-((float)(2 * j) / 128.f) * 13.287712379549449f);
    float ang = 2.f * (float)t * freq;
    float sv, cv;
    sincosf(ang, &sv, &cv);
    float2 r; r.x = cv; r.y = sv;
    tab[id] = r;
}

// ---------------- NT GEMM: C[m][n] = sum_k A[m][k] * B[n][k] ----------------
// 256x256 tile, BK=32, 512 thr / 8 waves (2M x 4N), wave tile 128x64, acc[8][4].
// LDS 128KB: 4 slots x 16384 u16 (A 256x32 @+0, B 256x32 @+8192), slot = t&3.
// DEPTH-3 PREFETCH (the fix for 1-resident-block latency exposure): tile t+3's
// A staged at t.P0, B at t.P1 -> each tile's loads get ~6 phases (>= HBM-miss
// latency) to land. ONE counted gate per tile: vmcnt(8) at P0 (tiles t+1,t+2 =
// 8 loads stay in flight; tail: 4 at t=niter-2, 0 at last). Reads stay
// POST-barrier (R4/R5 pre-barrier reads spilled: 128 AGPR acc + cross-barrier
// fragments > 256). Fragment peak here = a[4]+b[4] = 32 VGPR.
// Race: write slot (t+3)&3 != read slots {t,t+1,t+2}&3; slot reuse is fenced by
// the next tile's P0 barrier (ds_reads retire into VGPRs before the barrier).
// Swizzle (64B rows, 4 chunks): src chunk = kc ^ ((row>>1)&3); reader applies
// same XOR -> 16-lane ds_read_b128 covers 8 bank-groups = 2-way = free.
// MODE 0: fused QKV; rope+scale epilogue (2 heads per n-tile); V transposed.
// MODE 1: fp32 Out (M x 2048)
template <int MODE>
__global__ __launch_bounds__(512, 2) void gemm_nt(const u16* __restrict__ A, const u16* __restrict__ Bw,
                                                  u16* __restrict__ Qo, u16* __restrict__ Ko,
                                                  u16* __restrict__ Vt, float* __restrict__ Out,
                                                  const float2* __restrict__ tab, float qscale, int K) {
    extern __shared__ u16 smem[];   // 65536 u16 = 128KB
    const int tid = threadIdx.x;
    const int lane = tid & 63;
    const int qd = lane >> 4, ln = lane & 15;
    const int wid = tid >> 6;             // 0..7
    const int wr = wid >> 2, wc = wid & 3;

    constexpr int NBY = (MODE == 0) ? 24 : 8;
    const int id = (int)blockIdx.x;
    const int xcd = id & 7, slot = id >> 3;
    const int m0 = ((slot / NBY) * 8 + xcd) * 256;
    const int n0 = (slot % NBY) * 256;

    // staging: per matrix per K-tile: 1024 chunks (256 rows x 4 chunks), 2/thread
    int sr[2], skc[2];
#pragma unroll
    for (int l = 0; l < 2; ++l) {
        const int i = l * 512 + tid;
        sr[l] = i >> 2;
        skc[l] = (i & 3) ^ ((sr[l] >> 1) & 3);
    }

    auto stage = [&](int tt, int w) {     // w: 0=A, 1=B
        const u16* gp = w ? Bw : A;
        const int x0 = w ? n0 : m0;
        u16* lb = &smem[(tt & 3) * 16384 + w * 8192];
#pragma unroll
        for (int l = 0; l < 2; ++l)
            GLL16(gp + (size_t)(x0 + sr[l]) * K + tt * 32 + skc[l] * 8,
                  &lb[(l * 512 + tid) * 8]);
    };

    f32x4 acc[8][4];
#pragma unroll
    for (int mi = 0; mi < 8; ++mi)
#pragma unroll
        for (int ni = 0; ni < 4; ++ni) acc[mi][ni] = f32x4{0.f, 0.f, 0.f, 0.f};

    const int arow = (wr * 128 + ln) * 32;
    const int brow = (wc * 64 + ln) * 32;
    const int cx = (qd ^ ((ln >> 1) & 3)) * 8;   // swizzled k-chunk offset (u16)

    const int niter = K >> 5;   // 64 K-tiles
    // prologue: tiles 0,1,2 (12 loads)
    stage(0, 0); stage(0, 1);
    stage(1, 0); stage(1, 1);
    stage(2, 0); stage(2, 1);

    for (int t = 0; t < niter; ++t) {
        const u16* As = &smem[(t & 3) * 16384];
        const u16* Bs = As + 8192;
        // ---- P0: mi 0-3 x all n ----
        if (t < niter - 2)       asm volatile("s_waitcnt vmcnt(8)" ::: "memory");
        else if (t == niter - 2) asm volatile("s_waitcnt vmcnt(4)" ::: "memory");
        else                     asm volatile("s_waitcnt vmcnt(0)" ::: "memory");
        asm volatile("s_barrier" ::: "memory");
        bf16x8 a[4], b[4];
#pragma unroll
        for (int mi = 0; mi < 4; ++mi) a[mi] = *(const bf16x8*)&As[arow + mi * 512 + cx];
#pragma unroll
        for (int ni = 0; ni < 4; ++ni) b[ni] = *(const bf16x8*)&Bs[brow + ni * 512 + cx];
        if (t + 3 < niter) stage(t + 3, 0);
        __builtin_amdgcn_s_setprio(1);
#pragma unroll
        for (int mi = 0; mi < 4; ++mi)
#pragma unroll
            for (int ni = 0; ni < 4; ++ni)
                acc[mi][ni] = mfma16(a[mi], b[ni], acc[mi][ni]);
        __builtin_amdgcn_s_setprio(0);
        // ---- P1: mi 4-7 x all n (b reused) ----
        asm volatile("s_barrier" ::: "memory");
        bf16x8 a2[4];
#pragma unroll
        for (int mi = 0; mi < 4; ++mi) a2[mi] = *(const bf16x8*)&As[arow + (mi + 4) * 512 + cx];
        if (t + 3 < niter) stage(t + 3, 1);
        __builtin_amdgcn_s_setprio(1);
#pragma unroll
        for (int mi = 0; mi < 4; ++mi)
#pragma unroll
            for (int ni = 0; ni < 4; ++ni)
                acc[mi + 4][ni] = mfma16(a2[mi], b[ni], acc[mi + 4][ni]);
        __builtin_amdgcn_s_setprio(0);
    }
    __syncthreads();   // K-loop LDS dead; epilogue reuses all 128KB

    if constexpr (MODE == 0) {
        const int sec = n0 >> 11;   // 0=Q 1=K 2=V, uniform per block
        if (sec <= 1) {
            // stage C tile [m 256][d 256] bf16, chunk-swizzled: chunk' = (d>>3) ^ (m&15)
#pragma unroll
            for (int mi = 0; mi < 8; ++mi)
#pragma unroll
                for (int ni = 0; ni < 4; ++ni) {
                    const int col = wc * 64 + ni * 16 + ln;
                    const int cc = col >> 3, co = col & 7;
#pragma unroll
                    for (int r = 0; r < 4; ++r) {
                        const int row = wr * 128 + mi * 16 + qd * 4 + r;
                        smem[row * 256 + ((cc ^ (row & 15)) * 8) + co] = f2bf(acc[mi][ni][r]);
                    }
                }
            __syncthreads();
            const float qs = (sec == 0) ? qscale : 1.0f;
            u16* dstb = (sec == 0 ? Qo : Ko);
#pragma unroll
            for (int it = 0; it < 8; ++it) {
                const int c = it * 512 + tid;    // 4096 items: m (256) x head-in-tile (2) x lo-octet (8)
                const int m = c >> 4, hh = (c >> 3) & 1, d8 = c & 7;
                const u16x8 lo = *(const u16x8*)&smem[m * 256 + (((hh * 16 + d8) ^ (m & 15)) * 8)];
                const u16x8 hi = *(const u16x8*)&smem[m * 256 + (((hh * 16 + 8 + d8) ^ (m & 15)) * 8)];
                const int t = (m0 + m) & 2047;
                const float2* tb = tab + t * 64 + d8 * 8;
                u16x8 o1, o2;
#pragma unroll
                for (int i = 0; i < 8; ++i) {
                    const float x1 = bf2f(lo[i]), x2 = bf2f(hi[i]);
                    const float2 cs = tb[i];
                    o1[i] = f2bf((x1 * cs.x + x2 * cs.y) * qs);
                    o2[i] = f2bf((x2 * cs.x - x1 * cs.y) * qs);
                }
                u16* dst = dstb + (size_t)(m0 + m) * 2048 + (n0 & 2047) + hh * 128 + d8 * 8;
                *(u16x8*)dst = o1;
                *(u16x8*)(dst + 64) = o2;
            }
        } else {
            // V transpose: stage [nl 256][m 256] chunk-swizzled, stream rows of Vt
            const int bb = m0 >> 11;
#pragma unroll
            for (int mi = 0; mi < 8; ++mi) {
                const int mbase = wr * 128 + mi * 16 + qd * 4;
                const int mch = mbase >> 3, moff = mbase & 7;
#pragma unroll
                for (int ni = 0; ni < 4; ++ni) {
                    const int nl = wc * 64 + ni * 16 + ln;
                    u16x4 pk = { f2bf(acc[mi][ni][0]), f2bf(acc[mi][ni][1]),
                                 f2bf(acc[mi][ni][2]), f2bf(acc[mi][ni][3]) };
                    *(u16x4*)&smem[nl * 256 + ((mch ^ (nl & 15)) * 8) + moff] = pk;
                }
            }
            __syncthreads();
#pragma unroll
            for (int i = 0; i < 16; ++i) {
                const int c = i * 512 + tid;     // 8192 chunks
                const int nl = c >> 5, ch = c & 31;
                const u16x8 v = *(const u16x8*)&smem[nl * 256 + ch * 8];
                const int mch = ch ^ (nl & 15);
                const int hd = (n0 - 4096) + nl;
                *(u16x8*)&Vt[((size_t)(bb * 2048 + hd)) * 2048 + (m0 & 2047) + mch * 8] = v;
            }
        }
    } else {
        const int mg0 = m0 + wr * 128 + qd * 4;
        const int ng0 = n0 + wc * 64 + ln;
#pragma unroll
        for (int mi = 0; mi < 8; ++mi)
#pragma unroll
            for (int ni = 0; ni < 4; ++ni) {
                const int ng = ng0 + ni * 16;
#pragma unroll
                for (int r = 0; r < 4; ++r)
                    Out[(size_t)(mg0 + mi * 16 + r) * 2048 + ng] = acc[mi][ni][r];
            }
    }
}

// ---------------- causal flash attention ----------------
// 512 threads (8 waves x 16 q-rows), paired q-tiles {15-px, px} per block -> every
// block does exactly 34 k-iterations. 80KB LDS -> 2 blocks/CU -> 16 waves/CU.
// K-loop: raw s_barrier + counted vmcnt(4).
__global__ __launch_bounds__(512, 4) void attn_kernel(const u16* __restrict__ Qb, const u16* __restrict__ Kb,
                                                      const u16* __restrict__ Vt, u16* __restrict__ Yb) {
    extern __shared__ u16 smem[];
    u16* QP = smem;                 // 8192 u16: Q stage (64x128) / P buf (128x64)
    u16* KsB = smem + 8192;         // 2 x 8192 u16
    u16* VsB = smem + 8192 + 16384; // 2 x 8192 u16

    const int tid = threadIdx.x;
    const int lane = tid & 63;
    const int qd = lane >> 4, ln = lane & 15;
    const int wid = tid >> 6;            // 0..7
    const int id = (int)blockIdx.x;
    const int px = id >> 6;              // 0..7
    const int bh = id & 63;
    const int b = bh >> 4, h = bh & 15;

    const u16* Qbh = Qb + ((size_t)b * 2048 * 16 + h) * 128;
    const u16* Kbh = Kb + ((size_t)b * 2048 * 16 + h) * 128;
    const u16* Vbh = Vt + ((size_t)(b * 16 + h) * 128) * 2048;

    int lC[2], kOff[2], vOff[2];
#pragma unroll
    for (int p = 0; p < 2; ++p) {
        const int c = p * 512 + tid;     // 0..1023
        lC[p] = c * 8;
        { const int r = c >> 4, cc = (c & 15) ^ (r & 7); kOff[p] = r * 2048 + cc * 8; }
        { const int rv = c >> 3, cc = (c & 7) ^ (rv & 7); vOff[p] = rv * 2048 + cc * 8; }
    }

    bf16x8 onesf;
#pragma unroll
    for (int i = 0; i < 8; ++i) onesf[i] = (__bf16)1.0f;

    for (int half = 0; half < 2; ++half) {
        const int qt = half ? px : (15 - px);   // heavy tile first
        const int q0 = qt * 128;
        const int wq = q0 + wid * 16;
        const int nkt = 2 * qt + 2;

        __syncthreads();   // all waves done with QP (P buffer) before restaging Q
#pragma unroll
        for (int p = 0; p < 2; ++p)
            GLL16(Qbh + (size_t)q0 * 2048 + kOff[p], &QP[lC[p]]);
        __syncthreads();
        bf16x8 qf[4];
        if (wid < 4) {
            const int lr = wid * 16 + ln;
#pragma unroll
            for (int ks = 0; ks < 4; ++ks)
                qf[ks] = *(const bf16x8*)&QP[lr * 128 + (((ks * 4 + qd) ^ (lr & 7)) * 8)];
        }
        __syncthreads();
#pragma unroll
        for (int p = 0; p < 2; ++p)
            GLL16(Qbh + (size_t)(q0 + 64) * 2048 + kOff[p], &QP[lC[p]]);
        __syncthreads();
        if (wid >= 4) {
            const int lr = (wid - 4) * 16 + ln;
#pragma unroll
            for (int ks = 0; ks < 4; ++ks)
                qf[ks] = *(const bf16x8*)&QP[lr * 128 + (((ks * 4 + qd) ^ (lr & 7)) * 8)];
        }
        __syncthreads();   // readers drained before k-loop P writes reuse QP

#pragma unroll
        for (int p = 0; p < 2; ++p) GLL16(Kbh + kOff[p], &KsB[lC[p]]);
#pragma unroll
        for (int p = 0; p < 2; ++p) GLL16(Vbh + vOff[p], &VsB[lC[p]]);

        f32x4 o[8];
#pragma unroll
        for (int di = 0; di < 8; ++di) o[di] = f32x4{0.f, 0.f, 0.f, 0.f};
        f32x4 lacc = f32x4{0.f, 0.f, 0.f, 0.f};
        float Mr[4];
#pragma unroll
        for (int r = 0; r < 4; ++r) Mr[r] = -1e30f;

        for (int kt = 0; kt < nkt; ++kt) {
            const int k0 = kt * 64;
            asm volatile("s_barrier" ::: "memory");
            if (kt + 1 < nkt) {
                u16* kd = KsB + ((kt + 1) & 1) * 8192;
                u16* vd = VsB + ((kt + 1) & 1) * 8192;
#pragma unroll
                for (int p = 0; p < 2; ++p) GLL16(Kbh + (size_t)(k0 + 64) * 2048 + kOff[p], &kd[lC[p]]);
#pragma unroll
                for (int p = 0; p < 2; ++p) GLL16(Vbh + (size_t)(k0 + 64) + vOff[p], &vd[lC[p]]);
                asm volatile("s_waitcnt vmcnt(4)" ::: "memory");
            } else {
                asm volatile("s_waitcnt vmcnt(0)" ::: "memory");
            }
            asm volatile("s_barrier" ::: "memory");

            if (k0 <= wq + 15) {
                const u16* Kc = KsB + (kt & 1) * 8192;
                const u16* Vc = VsB + (kt & 1) * 8192;
                f32x4 s[4];
#pragma unroll
                for (int ni = 0; ni < 4; ++ni) s[ni] = f32x4{0.f, 0.f, 0.f, 0.f};
#pragma unroll
                for (int ks = 0; ks < 4; ++ks) {
                    bf16x8 kf[4];
#pragma unroll
                    for (int ni = 0; ni < 4; ++ni) {
                        const int row = ni * 16 + ln;
                        kf[ni] = *(const bf16x8*)&Kc[row * 128 + (((ks * 4 + qd) ^ (ln & 7)) * 8)];
                    }
#pragma unroll
                    for (int ni = 0; ni < 4; ++ni)
                        s[ni] = mfma16(qf[ks], kf[ni], s[ni]);
                }
                if (k0 + 63 > wq) {
#pragma unroll
                    for (int ni = 0; ni < 4; ++ni)
#pragma unroll
                        for (int r = 0; r < 4; ++r) {
                            const int qi = wq + qd * 4 + r;
                            const int ki = k0 + ni * 16 + ln;
                            if (ki > qi) s[ni][r] = -1e30f;
                        }
                }
                float rx[4];
#pragma unroll
                for (int r = 0; r < 4; ++r)
                    rx[r] = fmaxf(fmaxf(s[0][r], s[1][r]), fmaxf(s[2][r], s[3][r]));
#pragma unroll
                for (int st = 1; st < 16; st <<= 1)
#pragma unroll
                    for (int r = 0; r < 4; ++r)
                        rx[r] = fmaxf(rx[r], __shfl_xor(rx[r], st));
                float al[4];
                bool need = false;
#pragma unroll
                for (int r = 0; r < 4; ++r) {
                    const float nm = fmaxf(Mr[r], rx[r]);
                    al[r] = exp2f(Mr[r] - nm);
                    Mr[r] = nm;
                    need |= (al[r] != 1.0f);
                }
                if (__any(need)) {
#pragma unroll
                    for (int r = 0; r < 4; ++r) lacc[r] *= al[r];
#pragma unroll
                    for (int di = 0; di < 8; ++di)
#pragma unroll
                        for (int r = 0; r < 4; ++r) o[di][r] *= al[r];
                }
#pragma unroll
                for (int ni = 0; ni < 4; ++ni) {
                    const int cc0 = ni * 2 + (ln >> 3);
#pragma unroll
                    for (int r = 0; r < 4; ++r) {
                        const float p = exp2f(s[ni][r] - Mr[r]);
                        const int prow = wid * 16 + qd * 4 + r;
                        QP[prow * 64 + ((cc0 ^ ((prow >> 1) & 7)) * 8) + (ln & 7)] = f2bf(p);
                    }
                }
#pragma unroll
                for (int ks2 = 0; ks2 < 2; ++ks2) {
                    const int prow = wid * 16 + ln;
                    bf16x8 pf = *(const bf16x8*)&QP[prow * 64 + (((ks2 * 4 + qd) ^ ((prow >> 1) & 7)) * 8)];
                    lacc = mfma16(pf, onesf, lacc);
#pragma unroll
                    for (int di = 0; di < 8; ++di) {
                        const int row = di * 16 + ln;
                        bf16x8 vf = *(const bf16x8*)&Vc[row * 64 + (((ks2 * 4 + qd) ^ (ln & 7)) * 8)];
                        o[di] = mfma16(pf, vf, o[di]);
                    }
                }
            }
        }

        float inv[4];
#pragma unroll
        for (int r = 0; r < 4; ++r) inv[r] = 1.f / lacc[r];
#pragma unroll
        for (int di = 0; di < 8; ++di)
#pragma unroll
            for (int r = 0; r < 4; ++r) {
                const int t = q0 + wid * 16 + qd * 4 + r;
                const int d = di * 16 + ln;
                Yb[((size_t)((b * 2048 + t) * 16 + h)) * 128 + d] = f2bf(o[di][r] * inv[r]);
            }
    }
}

// ---------------- launch ----------------
extern "C" void kernel_launch(void* const* d_in, const int* in_sizes, int n_in,
                              void* d_out, int out_size, void* d_ws, size_t ws_size,
                              hipStream_t stream) {
    const float* x  = (const float*)d_in[0];
    const float* wq = (const float*)d_in[1];
    const float* wk = (const float*)d_in[2];
    const float* wv = (const float*)d_in[3];
    const float* wo = (const float*)d_in[4];
    float* out = (float*)d_out;
    char* ws = (char*)d_ws;

    u16* xb     = (u16*)(ws);                          // 8192x2048 bf16; reused as Y after attn
    u16* wqkv   = (u16*)(ws + (size_t)33554432);       // 6144x2048 bf16
    u16* wob    = (u16*)(ws + (size_t)58720256);       // 2048x2048 bf16
    u16* Qb     = (u16*)(ws + (size_t)67108864);       // (B,T,H,D) bf16, pre-scaled by 1/sqrt(D)*log2e
    u16* Kb     = (u16*)(ws + (size_t)100663296);      // (B,T,H,D) bf16
    u16* Vt     = (u16*)(ws + (size_t)134217728);      // (B,H,D,T) bf16
    float2* tab = (float2*)(ws + (size_t)167772160);   // 2048x64 cos/sin(2theta)
    u16* Yb = xb;

    const float scl = 0.08838834764831845f * 1.4426950408889634f;

    cvt_f32_bf16<<<16384, 256, 0, stream>>>(x, xb, 4194304);
    cvt_f32_bf16<<<4096, 256, 0, stream>>>(wq, wqkv, 1048576);
    cvt_f32_bf16<<<4096, 256, 0, stream>>>(wk, wqkv + 4194304, 1048576);
    cvt_f32_bf16<<<4096, 256, 0, stream>>>(wv, wqkv + 8388608, 1048576);
    cvt_f32_bf16<<<4096, 256, 0, stream>>>(wo, wob, 1048576);
    rope_table_k<<<512, 256, 0, stream>>>(tab);

    hipFuncSetAttribute((const void*)gemm_nt<0>, hipFuncAttributeMaxDynamicSharedMemorySize, 131072);
    hipFuncSetAttribute((const void*)gemm_nt<1>, hipFuncAttributeMaxDynamicSharedMemorySize, 131072);

    gemm_nt<0><<<dim3(768), 512, 131072, stream>>>(xb, wqkv, Qb, Kb, Vt, nullptr, tab, scl, 2048);

    hipFuncSetAttribute((const void*)attn_kernel, hipFuncAttributeMaxDynamicSharedMemorySize, 81920);
    attn_kernel<<<dim3(512), 512, 81920, stream>>>(Qb, Kb, Vt, Yb);

    gemm_nt<1><<<dim3(256), 512, 131072, stream>>>(Yb, wob, nullptr, nullptr, nullptr, out, tab, 1.0f, 2048);
}